// Round 12
// baseline (445.726 us; speedup 1.0000x reference)
//
#include <hip/hip_runtime.h>

#define HW 512
#define NPIX (HW*HW)
#define NSAMP 64
#define KSEL 2621
#define NF 3
#define NQ (NF*NSAMP)
#define CAP 16384
#define CPAD 32     // counter padding (uints) -> 128B apart, no false sharing
#define SBCAP 2048  // per-block candidate buffer (E~292/block, huge margin)

#define HALO 3
#define LSTR 520    // LDS row stride in floats (16B-aligned, bank-friendly)
#define ROWS 16
#define TR (ROWS + 2*HALO)   // 22
#define NV4 (TR*128)         // staged float4 per strip = 2816

// Analytic bracket: sim ~ N(0, ||w||^2) exactly (x iid normal). Single-sided:
// candidates = all |bits| >= T_lo; E[count] ~ 9.4K in [KSEL, CAP], ~70 sigma
// margins. Exactness never depends on it: violations poison -> full-plane
// radix fallback in sel_final.
#define Z_LO 2.1

// ===========================================================================
// Row-streaming conv (round-5 lesson: small live set, no spills).
// ===========================================================================
template<int K, int R>
__device__ __forceinline__ void conv_rows_f64(
    const float (*xt)[LSTR], const double* __restrict__ wsm,
    int tx, double* __restrict__ acc)
{
  constexpr int ROFF = HALO - K/2;
  constexpr int COFF = 4 - K/2;
  #pragma unroll
  for (int y = 0; y < R + K - 1; ++y) {
    double v[K];
    #pragma unroll
    for (int j = 0; j < K; ++j)
      v[j] = (double)xt[y + ROFF][tx + j + COFF];
    #pragma unroll
    for (int i = 0; i < K; ++i) {
      const int r = y - i;                 // compile-time after unroll
      if (r >= 0 && r < R) {
        #pragma unroll
        for (int j = 0; j < K; ++j)
          acc[r] = fma(v[j], wsm[i*K + j], acc[r]);
      }
    }
  }
}

template<int K, int R>
__device__ __forceinline__ void conv_rows_f32(
    const float (*xt)[LSTR], const float* __restrict__ wsm,
    int tx, float* __restrict__ acc)
{
  constexpr int ROFF = HALO - K/2;
  constexpr int COFF = 4 - K/2;
  #pragma unroll
  for (int y = 0; y < R + K - 1; ++y) {
    float v[K];
    #pragma unroll
    for (int j = 0; j < K; ++j)
      v[j] = xt[y + ROFF][tx + j + COFF];
    #pragma unroll
    for (int i = 0; i < K; ++i) {
      const int r = y - i;
      if (r >= 0 && r < R) {
        #pragma unroll
        for (int j = 0; j < K; ++j)
          acc[r] = fmaf(v[j], wsm[i*K + j], acc[r]);
      }
    }
  }
}

// Descending scans of LDS hist (coarse-256 + fine).
__device__ __forceinline__ void scan2048_desc(
    const unsigned* lh, unsigned* part, int t, unsigned kr,
    unsigned* out_bin, unsigned* out_krem)
{
  unsigned sum = 0;
  #pragma unroll
  for (int i = 0; i < 8; ++i) sum += lh[t*8 + i];
  part[t] = sum;
  __syncthreads();
  if (t == 0) {
    unsigned cum = 0; int sc = 0;
    for (int c = 255; c >= 0; --c) {
      if (cum + part[c] >= kr) { sc = c; break; }
      cum += part[c];
    }
    unsigned cum2 = cum; int sb = sc*8;
    for (int b = sc*8 + 7; b >= sc*8; --b) {
      if (cum2 + lh[b] >= kr) { sb = b; break; }
      cum2 += lh[b];
    }
    *out_bin = (unsigned)sb; *out_krem = kr - cum2;
  }
  __syncthreads();
}

__device__ __forceinline__ void scan512_desc(
    const unsigned* lh, unsigned* part, int t, unsigned kr,
    unsigned* out_bin)
{
  part[t] = lh[2*t] + lh[2*t + 1];
  __syncthreads();
  if (t == 0) {
    unsigned cum = 0; int sc = 0;
    for (int c = 255; c >= 0; --c) {
      if (cum + part[c] >= kr) { sc = c; break; }
      cum += part[c];
    }
    unsigned cum2 = cum; int sb = 2*sc;
    for (int b = 2*sc + 1; b >= 2*sc; --b) {
      if (cum2 + lh[b] >= kr) { sb = b; break; }
      cum2 += lh[b];
    }
    *out_bin = (unsigned)sb;
  }
  __syncthreads();
}

// ===========================================================================
// winit: analytic bracket threshold from ||w||_2 per filter.
// ===========================================================================
__global__ void winit(const float* __restrict__ w3, const float* __restrict__ w5,
                      const float* __restrict__ w7, unsigned* __restrict__ tlo)
{
  const int t = threadIdx.x;
  if (t < 3) {
    const float* w = (t == 0) ? w3 : (t == 1) ? w5 : w7;
    const int n = (t == 0) ? 9 : (t == 1) ? 25 : 49;
    double s2 = 0.0;
    for (int i = 0; i < n; ++i) s2 = fma((double)w[i], (double)w[i], s2);
    tlo[t] = __float_as_uint((float)(Z_LO * sqrt(s2)));
  }
}

// ===========================================================================
// Forward: fp64 conv (exact selection) with PER-FILTER wsm staging — the
// ds_write+barrier is the dependency fence that stops the scheduler from
// interleaving filter stages (round-11 lesson: preloaded weights let regalloc
// merge three acc[16] f64 live ranges -> 235MB scratch writes despite
// barriers). Thin single-sided compaction epilogue (~0.3% of elements).
// ===========================================================================
__global__ __launch_bounds__(512, 2) void fwd_all(
    const float* __restrict__ x,
    const float* __restrict__ w3, const float* __restrict__ w5,
    const float* __restrict__ w7,
    float* __restrict__ sims,
    const unsigned* __restrict__ tlo,
    unsigned* __restrict__ cntC, unsigned* __restrict__ cand)
{
  __shared__ float xt[TR][LSTR];
  __shared__ double wsm[49];
  __shared__ unsigned sb[SBCAP];
  __shared__ unsigned scnt, sbase;

  const int tid = threadIdx.x;
  const int s  = blockIdx.y;
  const int by = blockIdx.x * ROWS;
  const float* __restrict__ xs = x + (size_t)s*NPIX;
  const float* const wp[NF] = {w3, w5, w7};

  if (tid == 0) scnt = 0;
  if (tid < TR*8) {
    const int r = tid >> 3, c = tid & 7;
    xt[r][(c < 4) ? c : 512 + c] = 0.0f;
  }
  #pragma unroll 2
  for (int idx = tid; idx < NV4; idx += 512) {
    const int r = idx >> 7, c4 = idx & 127;
    const int gy = by + r - HALO;
    float4 v = make_float4(0.f, 0.f, 0.f, 0.f);
    if (gy >= 0 && gy < HW)
      v = ((const float4*)(xs + (size_t)gy*HW))[c4];
    *(float4*)&xt[r][4 + 4*c4] = v;
  }

  const int tx = tid;
  const size_t obase = (size_t)s*NPIX + (size_t)by*HW + tx;

  #pragma unroll
  for (int f = 0; f < NF; ++f) {
    const int K = 3 + 2*f;
    // fence: wsm write (+ scnt reset) between filter stages
    if (f > 0) {
      __syncthreads();                  // prev merge's sb reads done
      if (tid == 0) scnt = 0;
    }
    if (tid < K*K) wsm[tid] = (double)wp[f][tid];
    __syncthreads();                    // wsm/scnt/staging ready

    const unsigned Tl = tlo[f];
    const int q = f*NSAMP + s;

    double acc[ROWS];
    #pragma unroll
    for (int r = 0; r < ROWS; ++r) acc[r] = 0.0;
    if (f == 0)      conv_rows_f64<3, ROWS>(xt, wsm, tx, acc);
    else if (f == 1) conv_rows_f64<5, ROWS>(xt, wsm, tx, acc);
    else             conv_rows_f64<7, ROWS>(xt, wsm, tx, acc);

    float* __restrict__ so = sims + (size_t)f*NSAMP*NPIX + obase;
    #pragma unroll
    for (int r = 0; r < ROWS; ++r) {
      const float sv = (float)acc[r];
      so[(size_t)r*HW] = sv;
      const unsigned bits = __float_as_uint(sv) & 0x7fffffffu;
      if (bits >= Tl) {
        const unsigned pos = atomicAdd(&scnt, 1u);
        if (pos < SBCAP) sb[pos] = bits;
      }
    }
    __syncthreads();                    // scnt/sb stable

    const unsigned nb = scnt;
    if (tid == 0) {
      sbase = nb ? atomicAdd(&cntC[(size_t)q*CPAD], nb) : 0u;
      if (nb > SBCAP) atomicAdd(&cntC[(size_t)q*CPAD], (unsigned)(CAP + 1)); // poison
    }
    __syncthreads();
    const unsigned base = sbase;
    const unsigned nstore = (nb < (unsigned)SBCAP) ? nb : (unsigned)SBCAP;
    for (unsigned i = tid; i < nstore; i += 512) {
      const unsigned pos = base + i;
      if (pos < CAP) cand[(size_t)q*CAP + pos] = sb[i];
    }
  }
}

// ===========================================================================
// Exact selection: all elements >= T_lo are in cand, so the KSEL-th largest
// overall is the KSEL-th largest in cand. 3-level radix on the compact list;
// full-plane fallback if bracket invalid/overflowed.
// ===========================================================================
__global__ __launch_bounds__(256) void sel_final(
    const unsigned* __restrict__ cntC, const unsigned* __restrict__ cand,
    const float* __restrict__ sims, unsigned* __restrict__ thb)
{
  __shared__ unsigned lh[2048];
  __shared__ unsigned part[256];
  __shared__ unsigned sbin, skrem;
  const int q = blockIdx.x, t = threadIdx.x;

  const unsigned nC = cntC[(size_t)q*CPAD];
  const unsigned* __restrict__ cq = cand + (size_t)q*CAP;
  const float*    __restrict__ sq = sims + (size_t)q*NPIX;
  const bool ok = (nC >= (unsigned)KSEL) && (nC <= (unsigned)CAP);
  const unsigned kr0 = (unsigned)KSEL;

  for (int i = t; i < 2048; i += 256) lh[i] = 0;
  __syncthreads();
  if (ok) {
    for (unsigned i = t; i < nC; i += 256) atomicAdd(&lh[cq[i] >> 20], 1u);
  } else {
    for (int i = t; i < NPIX; i += 256) {
      const unsigned b = __float_as_uint(sq[i]) & 0x7fffffffu;
      atomicAdd(&lh[b >> 20], 1u);
    }
  }
  __syncthreads();
  scan2048_desc(lh, part, t, kr0, &sbin, &skrem);
  const unsigned pfx1 = sbin << 20;
  const unsigned kr1  = skrem;

  for (int i = t; i < 2048; i += 256) lh[i] = 0;
  __syncthreads();
  if (ok) {
    for (unsigned i = t; i < nC; i += 256) {
      const unsigned b = cq[i];
      if ((b >> 20) == (pfx1 >> 20)) atomicAdd(&lh[(b >> 9) & 0x7ffu], 1u);
    }
  } else {
    for (int i = t; i < NPIX; i += 256) {
      const unsigned b = __float_as_uint(sq[i]) & 0x7fffffffu;
      if ((b >> 20) == (pfx1 >> 20)) atomicAdd(&lh[(b >> 9) & 0x7ffu], 1u);
    }
  }
  __syncthreads();
  scan2048_desc(lh, part, t, kr1, &sbin, &skrem);
  const unsigned pfx2 = pfx1 | (sbin << 9);
  const unsigned kr2  = skrem;

  for (int i = t; i < 512; i += 256) lh[i] = 0;
  __syncthreads();
  if (ok) {
    for (unsigned i = t; i < nC; i += 256) {
      const unsigned b = cq[i];
      if ((b >> 9) == (pfx2 >> 9)) atomicAdd(&lh[b & 0x1ffu], 1u);
    }
  } else {
    for (int i = t; i < NPIX; i += 256) {
      const unsigned b = __float_as_uint(sq[i]) & 0x7fffffffu;
      if ((b >> 9) == (pfx2 >> 9)) atomicAdd(&lh[b & 0x1ffu], 1u);
    }
  }
  __syncthreads();
  scan512_desc(lh, part, t, kr2, &sbin);
  if (t == 0) thb[q] = pfx2 | sbin;
}

// ===========================================================================
// Backward: per-filter stage -> sync -> conv -> sync, per-filter wsm staging
// (same fence rationale as fwd). unroll 2 on staging to limit live float4s.
// ===========================================================================
__global__ __launch_bounds__(512, 2) void bwd_all(
    const float* __restrict__ sims,
    const float* __restrict__ w3, const float* __restrict__ w5,
    const float* __restrict__ w7,
    const unsigned* __restrict__ thb, float* __restrict__ out)
{
  __shared__ float xt[TR][LSTR];
  __shared__ float wsm[49];

  const int tid = threadIdx.x;
  const int s  = blockIdx.y;
  const int by = blockIdx.x * ROWS;
  const int tx = tid;
  const float* const wp[NF] = {w3, w5, w7};

  if (tid < TR*8) {
    const int r = tid >> 3, c = tid & 7;
    xt[r][(c < 4) ? c : 512 + c] = 0.0f;
  }

  float acc[ROWS];
  #pragma unroll
  for (int r = 0; r < ROWS; ++r) acc[r] = 0.0f;

  #pragma unroll
  for (int f = 0; f < NF; ++f) {
    const int K = 3 + 2*f;
    __syncthreads();                    // pads done / prev conv done
    if (tid < K*K) wsm[tid] = wp[f][tid];
    const unsigned th = thb[f*NSAMP + s];
    const float* __restrict__ ss = sims + ((size_t)f*NSAMP + s)*NPIX;

    #pragma unroll 2
    for (int idx = tid; idx < NV4; idx += 512) {
      const int r = idx >> 7, c4 = idx & 127;
      const int gy = by + r - HALO;
      float4 v = make_float4(0.f, 0.f, 0.f, 0.f);
      if (gy >= 0 && gy < HW) {
        v = ((const float4*)(ss + (size_t)gy*HW))[c4];
        if ((__float_as_uint(v.x) & 0x7fffffffu) < th) v.x = 0.0f;
        if ((__float_as_uint(v.y) & 0x7fffffffu) < th) v.y = 0.0f;
        if ((__float_as_uint(v.z) & 0x7fffffffu) < th) v.z = 0.0f;
        if ((__float_as_uint(v.w) & 0x7fffffffu) < th) v.w = 0.0f;
      }
      *(float4*)&xt[r][4 + 4*c4] = v;
    }
    __syncthreads();

    if (f == 0)      conv_rows_f32<3, ROWS>(xt, wsm, tx, acc);
    else if (f == 1) conv_rows_f32<5, ROWS>(xt, wsm, tx, acc);
    else             conv_rows_f32<7, ROWS>(xt, wsm, tx, acc);
  }

  float* __restrict__ oo = out + (size_t)s*NPIX + (size_t)by*HW + tx;
  #pragma unroll
  for (int r = 0; r < ROWS; ++r)
    oo[(size_t)r*HW] = acc[r];
}

// ===========================================================================
extern "C" void kernel_launch(void* const* d_in, const int* in_sizes, int n_in,
                              void* d_out, int out_size, void* d_ws, size_t ws_size,
                              hipStream_t stream)
{
  const float* x  = (const float*)d_in[0];
  const float* w3 = (const float*)d_in[1];
  const float* w5 = (const float*)d_in[2];
  const float* w7 = (const float*)d_in[3];
  float* out = (float*)d_out;
  char* ws = (char*)d_ws;

  const size_t SIMS_B = (size_t)NF*NSAMP*NPIX*sizeof(float);   // 192 MB
  const size_t CNT_B  = (size_t)NQ*CPAD*sizeof(unsigned);      // 24 KB

  float*    sims = (float*)ws;
  unsigned* cntC = (unsigned*)(ws + SIMS_B);
  unsigned* tlo  = cntC + (size_t)NQ*CPAD;
  unsigned* thb  = tlo + 8;
  unsigned* cand = thb + NQ + NQ;      // spare NQ gap

  hipMemsetAsync(cntC, 0, CNT_B, stream);

  winit<<<1, 64, 0, stream>>>(w3, w5, w7, tlo);
  dim3 b512(512, 1, 1);
  dim3 sg(HW/ROWS, NSAMP, 1);          // 32 x 64 strips
  fwd_all<<<sg, b512, 0, stream>>>(x, w3, w5, w7, sims, tlo, cntC, cand);
  sel_final<<<NQ, 256, 0, stream>>>(cntC, cand, sims, thb);
  bwd_all<<<sg, b512, 0, stream>>>(sims, w3, w5, w7, thb, out);
}

// Round 13
// 400.128 us; speedup vs baseline: 1.1140x; 1.1140x over previous
//
#include <hip/hip_runtime.h>

#define HW 512
#define NPIX (HW*HW)
#define NSAMP 64
#define KSEL 2621
#define NF 3
#define NQ (NF*NSAMP)
#define CAP 16384
#define CPAD 32     // counter padding (uints) -> 128B apart, no false sharing
#define SBCAP 2048  // per-block candidate buffer (E~292/block, huge margin)

#define HALO 3
#define LSTR 520    // LDS row stride in floats (2080B, 16B-aligned rows)
#define ROWS 16
#define TR (ROWS + 2*HALO)   // 22
#define NV4 (TR*128)         // staged float4 per strip = 2816

// Analytic bracket: sim ~ N(0, ||w||^2) exactly (x iid normal). Candidates =
// all |bits| >= T_lo; E[count] ~ 9.4K in [KSEL, CAP], ~70 sigma margins.
// Exactness never depends on it: violations poison -> full-plane fallback.
#define Z_LO 2.1

// ===========================================================================
// 4x4-outputs-per-thread conv core (round-12 lesson: 1-col/thread scalar LDS
// reads put 48us on the serialized DS pipe; 3 aligned ds_read_b128 per row
// serve 4 columns -> DS instructions drop 4.3x). Thread = (cg 0..127, rg 0..3),
// outputs rows rg*4..+3, cols 4*cg..+3.
// ===========================================================================
template<int K>
__device__ __forceinline__ void conv4x4_f64(
    const float (*xt)[LSTR], const double* __restrict__ wsm,
    int cg, int rg, double (*acc)[4])
{
  constexpr int P = K/2;
  #pragma unroll
  for (int y = 0; y < 4 + 2*P; ++y) {
    const int yy = rg*4 + HALO - P + y;
    const float4 a = *(const float4*)&xt[yy][4*cg];
    const float4 b = *(const float4*)&xt[yy][4*cg + 4];
    const float4 c = *(const float4*)&xt[yy][4*cg + 8];
    const float fl[12] = {a.x,a.y,a.z,a.w, b.x,b.y,b.z,b.w, c.x,c.y,c.z,c.w};
    double d[4 + 2*P];
    #pragma unroll
    for (int m = 0; m < 4 + 2*P; ++m) d[m] = (double)fl[4 - P + m];
    #pragma unroll
    for (int ip = 0; ip < K; ++ip) {
      const int rr = y - ip;               // compile-time after unroll
      if (rr >= 0 && rr < 4) {
        #pragma unroll
        for (int j = 0; j < K; ++j) {
          const double wv = wsm[ip*K + j];
          #pragma unroll
          for (int cc = 0; cc < 4; ++cc)
            acc[rr][cc] = fma(d[cc + j], wv, acc[rr][cc]);
        }
      }
    }
  }
}

template<int K>
__device__ __forceinline__ void conv4x4_f32(
    const float (*xt)[LSTR], const float* __restrict__ wsm,
    int cg, int rg, float (*acc)[4])
{
  constexpr int P = K/2;
  #pragma unroll
  for (int y = 0; y < 4 + 2*P; ++y) {
    const int yy = rg*4 + HALO - P + y;
    const float4 a = *(const float4*)&xt[yy][4*cg];
    const float4 b = *(const float4*)&xt[yy][4*cg + 4];
    const float4 c = *(const float4*)&xt[yy][4*cg + 8];
    const float fl[12] = {a.x,a.y,a.z,a.w, b.x,b.y,b.z,b.w, c.x,c.y,c.z,c.w};
    #pragma unroll
    for (int ip = 0; ip < K; ++ip) {
      const int rr = y - ip;
      if (rr >= 0 && rr < 4) {
        #pragma unroll
        for (int j = 0; j < K; ++j) {
          const float wv = wsm[ip*K + j];
          #pragma unroll
          for (int cc = 0; cc < 4; ++cc)
            acc[rr][cc] = fmaf(fl[4 - P + cc + j], wv, acc[rr][cc]);
        }
      }
    }
  }
}

// Descending scans of LDS hist (coarse-256 + fine).
__device__ __forceinline__ void scan2048_desc(
    const unsigned* lh, unsigned* part, int t, unsigned kr,
    unsigned* out_bin, unsigned* out_krem)
{
  unsigned sum = 0;
  #pragma unroll
  for (int i = 0; i < 8; ++i) sum += lh[t*8 + i];
  part[t] = sum;
  __syncthreads();
  if (t == 0) {
    unsigned cum = 0; int sc = 0;
    for (int c = 255; c >= 0; --c) {
      if (cum + part[c] >= kr) { sc = c; break; }
      cum += part[c];
    }
    unsigned cum2 = cum; int sb = sc*8;
    for (int b = sc*8 + 7; b >= sc*8; --b) {
      if (cum2 + lh[b] >= kr) { sb = b; break; }
      cum2 += lh[b];
    }
    *out_bin = (unsigned)sb; *out_krem = kr - cum2;
  }
  __syncthreads();
}

__device__ __forceinline__ void scan512_desc(
    const unsigned* lh, unsigned* part, int t, unsigned kr,
    unsigned* out_bin)
{
  part[t] = lh[2*t] + lh[2*t + 1];
  __syncthreads();
  if (t == 0) {
    unsigned cum = 0; int sc = 0;
    for (int c = 255; c >= 0; --c) {
      if (cum + part[c] >= kr) { sc = c; break; }
      cum += part[c];
    }
    unsigned cum2 = cum; int sb = 2*sc;
    for (int b = 2*sc + 1; b >= 2*sc; --b) {
      if (cum2 + lh[b] >= kr) { sb = b; break; }
      cum2 += lh[b];
    }
    *out_bin = (unsigned)sb;
  }
  __syncthreads();
}

// ===========================================================================
// winit: analytic bracket threshold from ||w||_2 per filter.
// ===========================================================================
__global__ void winit(const float* __restrict__ w3, const float* __restrict__ w5,
                      const float* __restrict__ w7, unsigned* __restrict__ tlo)
{
  const int t = threadIdx.x;
  if (t < 3) {
    const float* w = (t == 0) ? w3 : (t == 1) ? w5 : w7;
    const int n = (t == 0) ? 9 : (t == 1) ? 25 : 49;
    double s2 = 0.0;
    for (int i = 0; i < n; ++i) s2 = fma((double)w[i], (double)w[i], s2);
    tlo[t] = __float_as_uint((float)(Z_LO * sqrt(s2)));
  }
}

// ===========================================================================
// Forward, ONE FILTER PER KERNEL (round-12 lesson: the fused 3-filter fwd
// spilled at the 128-VGPR cap in every variant — splitting gives the
// allocator a single acc[4][4] f64 live range). fp64 conv -> exact selection.
// Single-sided compaction epilogue (~0.3% of elements).
// ===========================================================================
template<int K>
__global__ __launch_bounds__(512, 2) void fwd_k(
    const float* __restrict__ x, const float* __restrict__ w,
    float* __restrict__ sims, const unsigned* __restrict__ tlo, int f,
    unsigned* __restrict__ cntC, unsigned* __restrict__ cand)
{
  __shared__ float xt[TR][LSTR];
  __shared__ double wsm[K*K];
  __shared__ unsigned sb[SBCAP];
  __shared__ unsigned scnt, sbase;

  const int tid = threadIdx.x;
  const int s  = blockIdx.y;
  const int by = blockIdx.x * ROWS;
  const float* __restrict__ xs = x + (size_t)s*NPIX;

  if (tid < K*K) wsm[tid] = (double)w[tid];
  if (tid == 0) scnt = 0;
  if (tid < TR*8) {
    const int r = tid >> 3, c = tid & 7;
    xt[r][(c < 4) ? c : 512 + c] = 0.0f;
  }
  #pragma unroll 2
  for (int idx = tid; idx < NV4; idx += 512) {
    const int r = idx >> 7, c4 = idx & 127;
    const int gy = by + r - HALO;
    float4 v = make_float4(0.f, 0.f, 0.f, 0.f);
    if (gy >= 0 && gy < HW)
      v = ((const float4*)(xs + (size_t)gy*HW))[c4];
    *(float4*)&xt[r][4 + 4*c4] = v;
  }
  __syncthreads();

  const int cg = tid & 127, rg = tid >> 7;
  double acc[4][4];
  #pragma unroll
  for (int rr = 0; rr < 4; ++rr)
    #pragma unroll
    for (int cc = 0; cc < 4; ++cc) acc[rr][cc] = 0.0;

  conv4x4_f64<K>(xt, wsm, cg, rg, acc);

  const unsigned Tl = tlo[f];
  const int q = f*NSAMP + s;
  float* __restrict__ so = sims + (size_t)f*NSAMP*NPIX + (size_t)s*NPIX
                         + (size_t)(by + rg*4)*HW + 4*cg;
  #pragma unroll
  for (int rr = 0; rr < 4; ++rr) {
    float4 o;
    o.x = (float)acc[rr][0]; o.y = (float)acc[rr][1];
    o.z = (float)acc[rr][2]; o.w = (float)acc[rr][3];
    *(float4*)&so[(size_t)rr*HW] = o;
    const float ov[4] = {o.x, o.y, o.z, o.w};
    #pragma unroll
    for (int cc = 0; cc < 4; ++cc) {
      const unsigned bits = __float_as_uint(ov[cc]) & 0x7fffffffu;
      if (bits >= Tl) {
        const unsigned pos = atomicAdd(&scnt, 1u);
        if (pos < SBCAP) sb[pos] = bits;
      }
    }
  }
  __syncthreads();

  const unsigned nb = scnt;
  if (tid == 0) {
    sbase = nb ? atomicAdd(&cntC[(size_t)q*CPAD], nb) : 0u;
    if (nb > SBCAP) atomicAdd(&cntC[(size_t)q*CPAD], (unsigned)(CAP + 1)); // poison
  }
  __syncthreads();
  const unsigned base = sbase;
  const unsigned nstore = (nb < (unsigned)SBCAP) ? nb : (unsigned)SBCAP;
  for (unsigned i = tid; i < nstore; i += 512) {
    const unsigned pos = base + i;
    if (pos < CAP) cand[(size_t)q*CAP + pos] = sb[i];
  }
}

// ===========================================================================
// Exact selection: all elements >= T_lo are in cand, so the KSEL-th largest
// overall = KSEL-th largest in cand. 3-level radix; full-plane fallback if
// bracket invalid/overflowed.
// ===========================================================================
__global__ __launch_bounds__(256) void sel_final(
    const unsigned* __restrict__ cntC, const unsigned* __restrict__ cand,
    const float* __restrict__ sims, unsigned* __restrict__ thb)
{
  __shared__ unsigned lh[2048];
  __shared__ unsigned part[256];
  __shared__ unsigned sbin, skrem;
  const int q = blockIdx.x, t = threadIdx.x;

  const unsigned nC = cntC[(size_t)q*CPAD];
  const unsigned* __restrict__ cq = cand + (size_t)q*CAP;
  const float*    __restrict__ sq = sims + (size_t)q*NPIX;
  const bool ok = (nC >= (unsigned)KSEL) && (nC <= (unsigned)CAP);
  const unsigned kr0 = (unsigned)KSEL;

  for (int i = t; i < 2048; i += 256) lh[i] = 0;
  __syncthreads();
  if (ok) {
    for (unsigned i = t; i < nC; i += 256) atomicAdd(&lh[cq[i] >> 20], 1u);
  } else {
    for (int i = t; i < NPIX; i += 256) {
      const unsigned b = __float_as_uint(sq[i]) & 0x7fffffffu;
      atomicAdd(&lh[b >> 20], 1u);
    }
  }
  __syncthreads();
  scan2048_desc(lh, part, t, kr0, &sbin, &skrem);
  const unsigned pfx1 = sbin << 20;
  const unsigned kr1  = skrem;

  for (int i = t; i < 2048; i += 256) lh[i] = 0;
  __syncthreads();
  if (ok) {
    for (unsigned i = t; i < nC; i += 256) {
      const unsigned b = cq[i];
      if ((b >> 20) == (pfx1 >> 20)) atomicAdd(&lh[(b >> 9) & 0x7ffu], 1u);
    }
  } else {
    for (int i = t; i < NPIX; i += 256) {
      const unsigned b = __float_as_uint(sq[i]) & 0x7fffffffu;
      if ((b >> 20) == (pfx1 >> 20)) atomicAdd(&lh[(b >> 9) & 0x7ffu], 1u);
    }
  }
  __syncthreads();
  scan2048_desc(lh, part, t, kr1, &sbin, &skrem);
  const unsigned pfx2 = pfx1 | (sbin << 9);
  const unsigned kr2  = skrem;

  for (int i = t; i < 512; i += 256) lh[i] = 0;
  __syncthreads();
  if (ok) {
    for (unsigned i = t; i < nC; i += 256) {
      const unsigned b = cq[i];
      if ((b >> 9) == (pfx2 >> 9)) atomicAdd(&lh[b & 0x1ffu], 1u);
    }
  } else {
    for (int i = t; i < NPIX; i += 256) {
      const unsigned b = __float_as_uint(sq[i]) & 0x7fffffffu;
      if ((b >> 9) == (pfx2 >> 9)) atomicAdd(&lh[b & 0x1ffu], 1u);
    }
  }
  __syncthreads();
  scan512_desc(lh, part, t, kr2, &sbin);
  if (t == 0) thb[q] = pfx2 | sbin;
}

// ===========================================================================
// Backward: fused across filters (acc must accumulate), 4x4 f32 core.
// Per-filter: stage thresholded sim (float4, unroll 2) -> sync -> conv.
// ===========================================================================
__global__ __launch_bounds__(512, 2) void bwd_all(
    const float* __restrict__ sims,
    const float* __restrict__ w3, const float* __restrict__ w5,
    const float* __restrict__ w7,
    const unsigned* __restrict__ thb, float* __restrict__ out)
{
  __shared__ float xt[TR][LSTR];
  __shared__ float wsm[49];

  const int tid = threadIdx.x;
  const int s  = blockIdx.y;
  const int by = blockIdx.x * ROWS;
  const float* const wp[NF] = {w3, w5, w7};

  if (tid < TR*8) {
    const int r = tid >> 3, c = tid & 7;
    xt[r][(c < 4) ? c : 512 + c] = 0.0f;
  }

  const int cg = tid & 127, rg = tid >> 7;
  float acc[4][4];
  #pragma unroll
  for (int rr = 0; rr < 4; ++rr)
    #pragma unroll
    for (int cc = 0; cc < 4; ++cc) acc[rr][cc] = 0.0f;

  #pragma unroll
  for (int f = 0; f < NF; ++f) {
    const int K = 3 + 2*f;
    __syncthreads();                    // pads done / prev conv done
    if (tid < K*K) wsm[tid] = wp[f][tid];
    const unsigned th = thb[f*NSAMP + s];
    const float* __restrict__ ss = sims + ((size_t)f*NSAMP + s)*NPIX;

    #pragma unroll 2
    for (int idx = tid; idx < NV4; idx += 512) {
      const int r = idx >> 7, c4 = idx & 127;
      const int gy = by + r - HALO;
      float4 v = make_float4(0.f, 0.f, 0.f, 0.f);
      if (gy >= 0 && gy < HW) {
        v = ((const float4*)(ss + (size_t)gy*HW))[c4];
        if ((__float_as_uint(v.x) & 0x7fffffffu) < th) v.x = 0.0f;
        if ((__float_as_uint(v.y) & 0x7fffffffu) < th) v.y = 0.0f;
        if ((__float_as_uint(v.z) & 0x7fffffffu) < th) v.z = 0.0f;
        if ((__float_as_uint(v.w) & 0x7fffffffu) < th) v.w = 0.0f;
      }
      *(float4*)&xt[r][4 + 4*c4] = v;
    }
    __syncthreads();

    if (f == 0)      conv4x4_f32<3>(xt, wsm, cg, rg, acc);
    else if (f == 1) conv4x4_f32<5>(xt, wsm, cg, rg, acc);
    else             conv4x4_f32<7>(xt, wsm, cg, rg, acc);
  }

  float* __restrict__ oo = out + (size_t)s*NPIX + (size_t)(by + rg*4)*HW + 4*cg;
  #pragma unroll
  for (int rr = 0; rr < 4; ++rr) {
    float4 o;
    o.x = acc[rr][0]; o.y = acc[rr][1]; o.z = acc[rr][2]; o.w = acc[rr][3];
    *(float4*)&oo[(size_t)rr*HW] = o;
  }
}

// ===========================================================================
extern "C" void kernel_launch(void* const* d_in, const int* in_sizes, int n_in,
                              void* d_out, int out_size, void* d_ws, size_t ws_size,
                              hipStream_t stream)
{
  const float* x  = (const float*)d_in[0];
  const float* w3 = (const float*)d_in[1];
  const float* w5 = (const float*)d_in[2];
  const float* w7 = (const float*)d_in[3];
  float* out = (float*)d_out;
  char* ws = (char*)d_ws;

  const size_t SIMS_B = (size_t)NF*NSAMP*NPIX*sizeof(float);   // 192 MB
  const size_t CNT_B  = (size_t)NQ*CPAD*sizeof(unsigned);      // 24 KB

  float*    sims = (float*)ws;
  unsigned* cntC = (unsigned*)(ws + SIMS_B);
  unsigned* tlo  = cntC + (size_t)NQ*CPAD;
  unsigned* thb  = tlo + 8;
  unsigned* cand = thb + NQ + NQ;      // spare NQ gap

  hipMemsetAsync(cntC, 0, CNT_B, stream);

  winit<<<1, 64, 0, stream>>>(w3, w5, w7, tlo);
  dim3 b512(512, 1, 1);
  dim3 sg(HW/ROWS, NSAMP, 1);          // 32 x 64 strips
  fwd_k<3><<<sg, b512, 0, stream>>>(x, w3, sims, tlo, 0, cntC, cand);
  fwd_k<5><<<sg, b512, 0, stream>>>(x, w5, sims, tlo, 1, cntC, cand);
  fwd_k<7><<<sg, b512, 0, stream>>>(x, w7, sims, tlo, 2, cntC, cand);
  sel_final<<<NQ, 256, 0, stream>>>(cntC, cand, sims, thb);
  bwd_all<<<sg, b512, 0, stream>>>(sims, w3, w5, w7, thb, out);
}